// Round 5
// baseline (172.184 us; speedup 1.0000x reference)
//
#include <hip/hip_runtime.h>

#define DD 256
#define BB 8
#define NA 360
#define CH 8            // h-chunks per angle
#define HC (DD / CH)    // 32 h-steps per chunk

typedef _Float16 half2_t __attribute__((ext_vector_type(2)));

#if defined(__has_builtin)
#if __has_builtin(__builtin_amdgcn_fdot2)
#define HAVE_FDOT2 1
#endif
#endif

__device__ __forceinline__ float fdot2(unsigned p, half2_t wp, float acc) {
#ifdef HAVE_FDOT2
    return __builtin_amdgcn_fdot2(__builtin_bit_cast(half2_t, p), wp, acc, false);
#else
    half2_t hp = __builtin_bit_cast(half2_t, p);
    return acc + (float)hp.x * (float)wp.x + (float)hp.y * (float)wp.y;
#endif
}

__device__ __forceinline__ half2_t pkrtz(float a, float b) {
    return __builtin_bit_cast(half2_t, __builtin_amdgcn_cvt_pkrtz(a, b));
}

__device__ __forceinline__ unsigned pk_rne(float a, float b) {
    unsigned short ua = __builtin_bit_cast(unsigned short, (_Float16)a);
    unsigned short ub = __builtin_bit_cast(unsigned short, (_Float16)b);
    return (unsigned)ua | ((unsigned)ub << 16);
}

// ws layout (4 MiB):
//   +0MB  pN class A : entry(y,j) = 8 dwords, dword b = [f16 img[y][2j].b,  f16 img[y][2j+1].b]
//   +1MB  pN class B : pixels (2j+1, 2j+2)  (j=127 pad -> 0)
//   +2MB  pT class A : same over transposed image imgT[r][c]=img[c][r]
//   +3MB  pT class B
// entry byte offset within a 2MB (A|B) block: cls<<20 | row<<12 | j<<5 (+16 for batches 4-7)

// ---- pack: 16x16 tiles -> pN-A and pT-A (f16 RNE) -------------------------
__global__ __launch_bounds__(256) void pack_f16(const float* __restrict__ x,
                                                char* __restrict__ ws) {
    __shared__ float t[BB][16][17];
    const int bx = blockIdx.x & 15, by = blockIdx.x >> 4;
    const int x0 = bx * 16, y0 = by * 16;
    const int r0 = threadIdx.x >> 4, c0 = threadIdx.x & 15;
#pragma unroll
    for (int b = 0; b < BB; ++b)
        t[b][r0][c0] = x[b * DD * DD + (y0 + r0) * DD + x0 + c0];
    __syncthreads();

    const int r  = threadIdx.x >> 4;        // 0..15
    const int jj = (threadIdx.x >> 1) & 7;  // 0..7
    const int h  = threadIdx.x & 1;         // batch half
    uint4 vN, vT;
    unsigned* dN = (unsigned*)&vN;
    unsigned* dT = (unsigned*)&vT;
#pragma unroll
    for (int i = 0; i < 4; ++i) {
        const int b = 4 * h + i;
        dN[i] = pk_rne(t[b][r][2 * jj],     t[b][r][2 * jj + 1]);
        dT[i] = pk_rne(t[b][2 * jj][r],     t[b][2 * jj + 1][r]);
    }
    char* pNA = ws;
    char* pTA = ws + (2u << 20);
    *(uint4*)(pNA + ((y0 + r) << 12) + ((x0 / 2 + jj) << 5) + h * 16) = vN;
    *(uint4*)(pTA + ((x0 + r) << 12) + ((y0 / 2 + jj) << 5) + h * 16) = vT;
}

// ---- derive class B from class A via 16-bit shifts ------------------------
__global__ __launch_bounds__(256) void derive_B(char* __restrict__ ws) {
    char* baseA = ws + (size_t)blockIdx.y * (2u << 20);
    char* baseB = baseA + (1u << 20);
    const int y = blockIdx.x;
    const int j = threadIdx.x >> 1;
    const int h = threadIdx.x & 1;
    const size_t off = ((size_t)y << 12) + ((size_t)j << 5) + h * 16;
    uint4 a0 = *(const uint4*)(baseA + off);
    uint4 a1 = (j < 127) ? *(const uint4*)(baseA + off + 32) : make_uint4(0, 0, 0, 0);
    uint4 b;
    b.x = (a0.x >> 16) | (a1.x << 16);
    b.y = (a0.y >> 16) | (a1.y << 16);
    b.z = (a0.z >> 16) | (a1.z << 16);
    b.w = (a0.w >> 16) | (a1.w << 16);
    *(uint4*)(baseB + off) = b;
}

// ---- radon gather: 4 loads + 16 v_dot2 per h-step -------------------------
__global__ __launch_bounds__(256) void radon_f16(const char* __restrict__ ws,
                                                 float* __restrict__ out) {
    const int a  = blockIdx.x;   // angle
    const int hc = blockIdx.y;   // h-chunk
    const int w  = threadIdx.x;  // output column

    const float ang = (float)a * 0.5f;
    const float t = ang * 0.017453292519943295f;
    const float s = sinf(t);
    const float c = cosf(t);

    const float uw  = (float)w - 127.5f;
    const float axN = fmaf(c, uw, 127.5f);
    const float ayN = fmaf(s, uw, 127.5f);

    // choose layout whose inner (pair) axis has the smaller per-h step
    const char* __restrict__ P;
    float ax, dx, ay, dy;        // inner = ax+dx*uh, row = ay+dy*uh
    if (fabsf(s) <= fabsf(c)) { P = ws;              ax = axN; dx = -s; ay = ayN; dy = c;  }
    else                      { P = ws + (2u << 20); ax = ayN; dx = c;  ay = axN; dy = -s; }

    float acc[BB];
#pragma unroll
    for (int b = 0; b < BB; ++b) acc[b] = 0.f;

    const int h0 = hc * HC;
#pragma unroll 2
    for (int i = 0; i < HC; ++i) {
        const float uh = (float)(h0 + i) - 127.5f;
        const float ix = fmaf(dx, uh, ax);
        const float iy = fmaf(dy, uh, ay);
        const float x0f = floorf(ix), y0f = floorf(iy);
        const float wx1 = ix - x0f, wy1 = iy - y0f;
        const float wx0 = 1.f - wx1, wy0 = 1.f - wy1;
        const int x0 = (int)x0f, y0 = (int)y0f;

        // x: pick class/entry so the 2-pixel pair covers ref's (x0, x0+1)
        const float vx0 = ((unsigned)x0 < 256u) ? wx0 : 0.f;
        const float vx1 = ((unsigned)(x0 + 1) < 256u) ? wx1 : 0.f;
        const bool sx = x0 < 0;
        const float wAx = sx ? vx1 : vx0;          // weight on pair elem 0
        const float wBx = sx ? 0.f : vx1;          // weight on pair elem 1
        const int cls = sx ? 0 : (x0 & 1);
        int j = sx ? 0 : (x0 >> 1);
        j = min(j, 127);

        // y: two rows with swap/clamp
        const float vy0 = ((unsigned)y0 < 256u) ? wy0 : 0.f;
        const float vy1 = ((unsigned)(y0 + 1) < 256u) ? wy1 : 0.f;
        const bool sy = y0 < 0;
        const float wr0 = sy ? vy1 : vy0;
        const float wr1 = sy ? 0.f : vy1;
        const int R0 = min(max(y0, 0), 255);
        const int R1 = min(max(y0 + 1, 0), 255);

        const half2_t wp0 = pkrtz(wr0 * wAx, wr0 * wBx);
        const half2_t wp1 = pkrtz(wr1 * wAx, wr1 * wBx);

        const unsigned offx = ((unsigned)cls << 20) | ((unsigned)j << 5);
        const uint4* e0 = (const uint4*)(P + (offx | ((unsigned)R0 << 12)));
        const uint4* e1 = (const uint4*)(P + (offx | ((unsigned)R1 << 12)));
        const uint4 qa0 = e0[0], qb0 = e0[1];
        const uint4 qa1 = e1[0], qb1 = e1[1];

        acc[0] = fdot2(qa0.x, wp0, acc[0]);
        acc[1] = fdot2(qa0.y, wp0, acc[1]);
        acc[2] = fdot2(qa0.z, wp0, acc[2]);
        acc[3] = fdot2(qa0.w, wp0, acc[3]);
        acc[4] = fdot2(qb0.x, wp0, acc[4]);
        acc[5] = fdot2(qb0.y, wp0, acc[5]);
        acc[6] = fdot2(qb0.z, wp0, acc[6]);
        acc[7] = fdot2(qb0.w, wp0, acc[7]);
        acc[0] = fdot2(qa1.x, wp1, acc[0]);
        acc[1] = fdot2(qa1.y, wp1, acc[1]);
        acc[2] = fdot2(qa1.z, wp1, acc[2]);
        acc[3] = fdot2(qa1.w, wp1, acc[3]);
        acc[4] = fdot2(qb1.x, wp1, acc[4]);
        acc[5] = fdot2(qb1.y, wp1, acc[5]);
        acc[6] = fdot2(qb1.z, wp1, acc[6]);
        acc[7] = fdot2(qb1.w, wp1, acc[7]);
    }

    const float sc = 1.0f / 256.0f;
#pragma unroll
    for (int b = 0; b < BB; ++b)
        atomicAdd(out + (size_t)b * NA * DD + (size_t)a * DD + w, acc[b] * sc);
}

// ---- fallback (ws too small): direct fp32 gather --------------------------
__global__ __launch_bounds__(256) void radon_direct(const float* __restrict__ x,
                                                    float* __restrict__ out) {
    const int a  = blockIdx.x;
    const int hc = blockIdx.y;
    const int w  = threadIdx.x;
    const float ang = (float)a * 0.5f;
    const float t = ang * 0.017453292519943295f;
    const float s = sinf(t);
    const float c = cosf(t);
    const float uw = (float)w - 127.5f;
    const float ax = fmaf(c, uw, 127.5f);
    const float ay = fmaf(s, uw, 127.5f);

    float acc[BB];
#pragma unroll
    for (int b = 0; b < BB; ++b) acc[b] = 0.f;

    const int h0 = hc * HC;
    for (int i = 0; i < HC; ++i) {
        const float uh = (float)(h0 + i) - 127.5f;
        const float ix = fmaf(-s, uh, ax);
        const float iy = fmaf(c, uh, ay);
        const float x0f = floorf(ix), y0f = floorf(iy);
        const float wx1 = ix - x0f, wy1 = iy - y0f;
        const float wx0 = 1.f - wx1, wy0 = 1.f - wy1;
        const int x0 = (int)x0f, y0 = (int)y0f;
        const float vx0 = ((unsigned)x0 < 256u) ? wx0 : 0.f;
        const float vx1 = ((unsigned)(x0 + 1) < 256u) ? wx1 : 0.f;
        const float vy0 = ((unsigned)y0 < 256u) ? wy0 : 0.f;
        const float vy1 = ((unsigned)(y0 + 1) < 256u) ? wy1 : 0.f;
        const int x0c = min(max(x0, 0), 255);
        const int x1c = min(max(x0 + 1, 0), 255);
        const int y0c = min(max(y0, 0), 255);
        const int y1c = min(max(y0 + 1, 0), 255);
        const float w00 = vx0 * vy0, w10 = vx1 * vy0;
        const float w01 = vx0 * vy1, w11 = vx1 * vy1;
        const int l00 = y0c * DD + x0c, l10 = y0c * DD + x1c;
        const int l01 = y1c * DD + x0c, l11 = y1c * DD + x1c;
#pragma unroll
        for (int b = 0; b < BB; ++b) {
            const float* ib = x + (size_t)b * DD * DD;
            acc[b] = fmaf(ib[l00], w00, acc[b]);
            acc[b] = fmaf(ib[l10], w10, acc[b]);
            acc[b] = fmaf(ib[l01], w01, acc[b]);
            acc[b] = fmaf(ib[l11], w11, acc[b]);
        }
    }

    const float sc = 1.0f / 256.0f;
    float* o = out + (size_t)a * DD + w;
#pragma unroll
    for (int b = 0; b < BB; ++b)
        atomicAdd(o + (size_t)b * NA * DD, acc[b] * sc);
}

extern "C" void kernel_launch(void* const* d_in, const int* in_sizes, int n_in,
                              void* d_out, int out_size, void* d_ws, size_t ws_size,
                              hipStream_t stream) {
    const float* x = (const float*)d_in[0];
    float* out = (float*)d_out;

    // atomic accumulation -> zero the poisoned output first
    (void)hipMemsetAsync(d_out, 0, (size_t)out_size * sizeof(float), stream);

    const size_t need = 4ull << 20;   // 4 MiB: pN A|B + pT A|B
    if (ws_size >= need) {
        char* ws = (char*)d_ws;
        pack_f16<<<256, 256, 0, stream>>>(x, ws);
        derive_B<<<dim3(256, 2), 256, 0, stream>>>(ws);
        radon_f16<<<dim3(NA, CH), 256, 0, stream>>>(ws, out);
    } else {
        radon_direct<<<dim3(NA, CH), 256, 0, stream>>>(x, out);
    }
}

// Round 6
// 130.405 us; speedup vs baseline: 1.3204x; 1.3204x over previous
//
#include <hip/hip_runtime.h>

#define DD 256
#define BB 8
#define NA 360

typedef _Float16 half2_t __attribute__((ext_vector_type(2)));

__device__ __forceinline__ unsigned pk_f16(float a, float b) {
    unsigned short ua = __builtin_bit_cast(unsigned short, (_Float16)a);
    unsigned short ub = __builtin_bit_cast(unsigned short, (_Float16)b);
    return (unsigned)ua | ((unsigned)ub << 16);
}

// acc[b] += f16(q)[b] * wgt   -- pattern folds to v_fma_mix_f32 (fpext f16 src)
__device__ __forceinline__ void mix8(uint4 q, float wgt, float* acc) {
    half2_t h;
    h = __builtin_bit_cast(half2_t, q.x);
    acc[0] = fmaf((float)h.x, wgt, acc[0]); acc[1] = fmaf((float)h.y, wgt, acc[1]);
    h = __builtin_bit_cast(half2_t, q.y);
    acc[2] = fmaf((float)h.x, wgt, acc[2]); acc[3] = fmaf((float)h.y, wgt, acc[3]);
    h = __builtin_bit_cast(half2_t, q.z);
    acc[4] = fmaf((float)h.x, wgt, acc[4]); acc[5] = fmaf((float)h.y, wgt, acc[5]);
    h = __builtin_bit_cast(half2_t, q.w);
    acc[6] = fmaf((float)h.x, wgt, acc[6]); acc[7] = fmaf((float)h.y, wgt, acc[7]);
}

// ---- pack: (B,1,D,D) fp32 -> f16x8-per-pixel pN (row-major) + pT (transposed)
__global__ __launch_bounds__(256) void pack_f16(const float* __restrict__ x,
                                                uint4* __restrict__ pN,
                                                uint4* __restrict__ pT) {
    __shared__ uint4 t[32][33];
    const int tx = threadIdx.x & 31;
    const int ty = threadIdx.x >> 5;              // 0..7
    const int x0 = (blockIdx.x & 7) * 32;
    const int y0 = (blockIdx.x >> 3) * 32;

#pragma unroll
    for (int r = ty; r < 32; r += 8) {
        const int pix = (y0 + r) * DD + x0 + tx;
        uint4 v;
        v.x = pk_f16(x[0 * DD * DD + pix], x[1 * DD * DD + pix]);
        v.y = pk_f16(x[2 * DD * DD + pix], x[3 * DD * DD + pix]);
        v.z = pk_f16(x[4 * DD * DD + pix], x[5 * DD * DD + pix]);
        v.w = pk_f16(x[6 * DD * DD + pix], x[7 * DD * DD + pix]);
        pN[pix] = v;                               // coalesced
        t[r][tx] = v;
    }
    __syncthreads();
#pragma unroll
    for (int r = ty; r < 32; r += 8)               // pT[xx*D+yy] = img[yy][xx]
        pT[(x0 + r) * DD + y0 + tx] = t[tx][r];    // coalesced store
}

// ---- radon: block = (angle, w-quarter); 4 waves = interleaved h; LDS reduce
__global__ __launch_bounds__(256) void radon_mix(const uint4* __restrict__ pN,
                                                 const uint4* __restrict__ pT,
                                                 float* __restrict__ out) {
    const int a    = blockIdx.x;            // angle
    const int wseg = blockIdx.y;            // 0..3
    const int g    = threadIdx.x >> 6;      // wave = h-phase 0..3
    const int lane = threadIdx.x & 63;
    const int w    = wseg * 64 + lane;

    const float ang = (float)a * 0.5f;
    const float t = ang * 0.017453292519943295f;
    const float s = sinf(t);
    const float c = cosf(t);

    const float uw  = (float)w - 127.5f;
    const float axN = fmaf(c, uw, 127.5f);
    const float ayN = fmaf(s, uw, 127.5f);

    // inner coord = contiguous dim of chosen layout (h-step = min(|s|,|c|))
    const uint4* __restrict__ P;
    float ax, dx, ay, dy;                    // inner = ax+dx*uh, outer = ay+dy*uh
    if (fabsf(s) <= fabsf(c)) { P = pN; ax = axN; dx = -s; ay = ayN; dy = c;  }
    else                      { P = pT; ax = ayN; dx = c;  ay = axN; dy = -s; }

    float acc[BB];
#pragma unroll
    for (int b = 0; b < BB; ++b) acc[b] = 0.f;

    // h = g + 4*i : the block's 4 waves march through adjacent h together
#pragma unroll 2
    for (int i = 0; i < 64; ++i) {
        const float uh = (float)(g + 4 * i) - 127.5f;
        const float ix = fmaf(dx, uh, ax);           // inner
        const float iy = fmaf(dy, uh, ay);           // outer (row)
        const float x0f = floorf(ix), y0f = floorf(iy);
        const float wx1 = ix - x0f, wy1 = iy - y0f;
        const float wx0 = 1.f - wx1, wy0 = 1.f - wy1;
        const int x0 = (int)x0f, y0 = (int)y0f;
        const float vx0 = ((unsigned)x0 < 256u) ? wx0 : 0.f;
        const float vx1 = ((unsigned)(x0 + 1) < 256u) ? wx1 : 0.f;
        const float vy0 = ((unsigned)y0 < 256u) ? wy0 : 0.f;
        const float vy1 = ((unsigned)(y0 + 1) < 256u) ? wy1 : 0.f;
        const int x0c = min(max(x0, 0), 255);
        const int x1c = min(max(x0 + 1, 0), 255);
        const int y0c = min(max(y0, 0), 255);
        const int y1c = min(max(y0 + 1, 0), 255);
        const float w00 = vx0 * vy0, w10 = vx1 * vy0;
        const float w01 = vx0 * vy1, w11 = vx1 * vy1;

        const uint4 q00 = P[y0c * DD + x0c];
        const uint4 q10 = P[y0c * DD + x1c];
        const uint4 q01 = P[y1c * DD + x0c];
        const uint4 q11 = P[y1c * DD + x1c];

        mix8(q00, w00, acc);
        mix8(q10, w10, acc);
        mix8(q01, w01, acc);
        mix8(q11, w11, acc);
    }

    // ---- in-block reduction over the 4 h-phases; one exclusive store/output
    __shared__ float part[4][64][BB];        // 8 KB
#pragma unroll
    for (int b = 0; b < BB; b += 4)
        *(float4*)&part[g][lane][b] = make_float4(acc[b], acc[b + 1], acc[b + 2], acc[b + 3]);
    __syncthreads();

    const float sc = 1.0f / 256.0f;
#pragma unroll
    for (int k = 0; k < 2; ++k) {
        const int id = threadIdx.x + k * 256;  // 0..511 -> (b, wl)
        const int b  = id >> 6;
        const int wl = id & 63;
        const float v = part[0][wl][b] + part[1][wl][b] + part[2][wl][b] + part[3][wl][b];
        out[(size_t)b * NA * DD + (size_t)a * DD + wseg * 64 + wl] = v * sc;
    }
}

// ---- fallback (ws too small): direct fp32 gather with atomics -------------
__global__ __launch_bounds__(256) void radon_direct(const float* __restrict__ x,
                                                    float* __restrict__ out) {
    const int a  = blockIdx.x;
    const int hc = blockIdx.y;
    const int w  = threadIdx.x;
    const float ang = (float)a * 0.5f;
    const float t = ang * 0.017453292519943295f;
    const float s = sinf(t);
    const float c = cosf(t);
    const float uw = (float)w - 127.5f;
    const float ax = fmaf(c, uw, 127.5f);
    const float ay = fmaf(s, uw, 127.5f);

    float acc[BB];
#pragma unroll
    for (int b = 0; b < BB; ++b) acc[b] = 0.f;

    const int h0 = hc * 32;
    for (int i = 0; i < 32; ++i) {
        const float uh = (float)(h0 + i) - 127.5f;
        const float ix = fmaf(-s, uh, ax);
        const float iy = fmaf(c, uh, ay);
        const float x0f = floorf(ix), y0f = floorf(iy);
        const float wx1 = ix - x0f, wy1 = iy - y0f;
        const float wx0 = 1.f - wx1, wy0 = 1.f - wy1;
        const int x0 = (int)x0f, y0 = (int)y0f;
        const float vx0 = ((unsigned)x0 < 256u) ? wx0 : 0.f;
        const float vx1 = ((unsigned)(x0 + 1) < 256u) ? wx1 : 0.f;
        const float vy0 = ((unsigned)y0 < 256u) ? wy0 : 0.f;
        const float vy1 = ((unsigned)(y0 + 1) < 256u) ? wy1 : 0.f;
        const int x0c = min(max(x0, 0), 255);
        const int x1c = min(max(x0 + 1, 0), 255);
        const int y0c = min(max(y0, 0), 255);
        const int y1c = min(max(y0 + 1, 0), 255);
        const float w00 = vx0 * vy0, w10 = vx1 * vy0;
        const float w01 = vx0 * vy1, w11 = vx1 * vy1;
        const int l00 = y0c * DD + x0c, l10 = y0c * DD + x1c;
        const int l01 = y1c * DD + x0c, l11 = y1c * DD + x1c;
#pragma unroll
        for (int b = 0; b < BB; ++b) {
            const float* ib = x + (size_t)b * DD * DD;
            acc[b] = fmaf(ib[l00], w00, acc[b]);
            acc[b] = fmaf(ib[l10], w10, acc[b]);
            acc[b] = fmaf(ib[l01], w01, acc[b]);
            acc[b] = fmaf(ib[l11], w11, acc[b]);
        }
    }

    const float sc = 1.0f / 256.0f;
    float* o = out + (size_t)a * DD + w;
#pragma unroll
    for (int b = 0; b < BB; ++b)
        atomicAdd(o + (size_t)b * NA * DD, acc[b] * sc);
}

extern "C" void kernel_launch(void* const* d_in, const int* in_sizes, int n_in,
                              void* d_out, int out_size, void* d_ws, size_t ws_size,
                              hipStream_t stream) {
    const float* x = (const float*)d_in[0];
    float* out = (float*)d_out;

    const size_t need = 2ull * DD * DD * sizeof(uint4);  // 2 MiB
    if (ws_size >= need) {
        uint4* pN = (uint4*)d_ws;
        uint4* pT = pN + (size_t)DD * DD;
        pack_f16<<<64, 256, 0, stream>>>(x, pN, pT);
        radon_mix<<<dim3(NA, 4), 256, 0, stream>>>(pN, pT, out);
    } else {
        (void)hipMemsetAsync(d_out, 0, (size_t)out_size * sizeof(float), stream);
        radon_direct<<<dim3(NA, 8), 256, 0, stream>>>(x, out);
    }
}

// Round 7
// 126.113 us; speedup vs baseline: 1.3653x; 1.0340x over previous
//
#include <hip/hip_runtime.h>

#define DD 256
#define BB 8
#define NA 360

typedef _Float16 half2_t __attribute__((ext_vector_type(2)));

#if defined(__has_builtin)
#if __has_builtin(__builtin_elementwise_fma)
#define PKFMA(a, b, c) __builtin_elementwise_fma((a), (b), (c))
#endif
#endif
#ifndef PKFMA
#define PKFMA(a, b, c) ((a) * (b) + (c))
#endif

__device__ __forceinline__ half2_t h2(unsigned u) {
    return __builtin_bit_cast(half2_t, u);
}
__device__ __forceinline__ half2_t bcast2(float w) {   // v_cvt_pkrtz: (w,w) as f16x2
    return __builtin_bit_cast(half2_t, __builtin_amdgcn_cvt_pkrtz(w, w));
}
__device__ __forceinline__ unsigned pk_f16(float a, float b) {
    unsigned short ua = __builtin_bit_cast(unsigned short, (_Float16)a);
    unsigned short ub = __builtin_bit_cast(unsigned short, (_Float16)b);
    return (unsigned)ua | ((unsigned)ub << 16);
}

// ---- pack: (B,1,D,D) fp32 -> f16x8-per-pixel pN (row-major) + pT (transposed)
__global__ __launch_bounds__(256) void pack_f16(const float* __restrict__ x,
                                                uint4* __restrict__ pN,
                                                uint4* __restrict__ pT) {
    __shared__ uint4 t[32][33];
    const int tx = threadIdx.x & 31;
    const int ty = threadIdx.x >> 5;              // 0..7
    const int x0 = (blockIdx.x & 7) * 32;
    const int y0 = (blockIdx.x >> 3) * 32;

#pragma unroll
    for (int r = ty; r < 32; r += 8) {
        const int pix = (y0 + r) * DD + x0 + tx;
        uint4 v;
        v.x = pk_f16(x[0 * DD * DD + pix], x[1 * DD * DD + pix]);
        v.y = pk_f16(x[2 * DD * DD + pix], x[3 * DD * DD + pix]);
        v.z = pk_f16(x[4 * DD * DD + pix], x[5 * DD * DD + pix]);
        v.w = pk_f16(x[6 * DD * DD + pix], x[7 * DD * DD + pix]);
        pN[pix] = v;                               // coalesced
        t[r][tx] = v;
    }
    __syncthreads();
#pragma unroll
    for (int r = ty; r < 32; r += 8)               // pT[xx*D+yy] = img[yy][xx]
        pT[(x0 + r) * DD + y0 + tx] = t[tx][r];    // coalesced store
}

// ---- radon: block = (angle, w-quarter); 4 waves = interleaved h; LDS reduce
// inner loop: 4 corner loads + 16 v_pk_fma_f16 (2 MACs each) per h-step
__global__ __launch_bounds__(256) void radon_pk(const uint4* __restrict__ pN,
                                                const uint4* __restrict__ pT,
                                                float* __restrict__ out) {
    const int a    = blockIdx.x;            // angle
    const int wseg = blockIdx.y;            // 0..3
    const int g    = threadIdx.x >> 6;      // wave = h-phase 0..3
    const int lane = threadIdx.x & 63;
    const int w    = wseg * 64 + lane;

    const float ang = (float)a * 0.5f;
    const float t = ang * 0.017453292519943295f;
    const float s = sinf(t);
    const float c = cosf(t);

    const float uw  = (float)w - 127.5f;
    const float axN = fmaf(c, uw, 127.5f);
    const float ayN = fmaf(s, uw, 127.5f);

    // inner coord = contiguous dim of chosen layout (h-step = min(|s|,|c|))
    const uint4* __restrict__ P;
    float ax, dx, ay, dy;                    // inner = ax+dx*uh, outer = ay+dy*uh
    if (fabsf(s) <= fabsf(c)) { P = pN; ax = axN; dx = -s; ay = ayN; dy = c;  }
    else                      { P = pT; ax = ayN; dx = c;  ay = axN; dy = -s; }

    half2_t acc2[4];                         // 8 batches as 4 f16 pairs
#pragma unroll
    for (int j = 0; j < 4; ++j) acc2[j] = half2_t{(_Float16)0, (_Float16)0};

    // h = g + 4*i : the block's 4 waves march through adjacent h together
#pragma unroll 4
    for (int i = 0; i < 64; ++i) {
        const float uh = (float)(g + 4 * i) - 127.5f;
        const float ix = fmaf(dx, uh, ax);           // inner
        const float iy = fmaf(dy, uh, ay);           // outer (row)
        const float x0f = floorf(ix), y0f = floorf(iy);
        const float wx1 = ix - x0f, wy1 = iy - y0f;
        const float wx0 = 1.f - wx1, wy0 = 1.f - wy1;
        const int x0 = (int)x0f, y0 = (int)y0f;
        const float vx0 = ((unsigned)x0 < 256u) ? wx0 : 0.f;
        const float vx1 = ((unsigned)(x0 + 1) < 256u) ? wx1 : 0.f;
        const float vy0 = ((unsigned)y0 < 256u) ? wy0 : 0.f;
        const float vy1 = ((unsigned)(y0 + 1) < 256u) ? wy1 : 0.f;
        const int x0c = min(max(x0, 0), 255);
        const int x1c = min(max(x0 + 1, 0), 255);
        const int y0c = min(max(y0, 0), 255);
        const int y1c = min(max(y0 + 1, 0), 255);

        const uint4 q00 = P[y0c * DD + x0c];
        const uint4 q10 = P[y0c * DD + x1c];
        const uint4 q01 = P[y1c * DD + x0c];
        const uint4 q11 = P[y1c * DD + x1c];

        const half2_t w00 = bcast2(vx0 * vy0);
        const half2_t w10 = bcast2(vx1 * vy0);
        const half2_t w01 = bcast2(vx0 * vy1);
        const half2_t w11 = bcast2(vx1 * vy1);

        acc2[0] = PKFMA(h2(q00.x), w00, acc2[0]);
        acc2[1] = PKFMA(h2(q00.y), w00, acc2[1]);
        acc2[2] = PKFMA(h2(q00.z), w00, acc2[2]);
        acc2[3] = PKFMA(h2(q00.w), w00, acc2[3]);
        acc2[0] = PKFMA(h2(q10.x), w10, acc2[0]);
        acc2[1] = PKFMA(h2(q10.y), w10, acc2[1]);
        acc2[2] = PKFMA(h2(q10.z), w10, acc2[2]);
        acc2[3] = PKFMA(h2(q10.w), w10, acc2[3]);
        acc2[0] = PKFMA(h2(q01.x), w01, acc2[0]);
        acc2[1] = PKFMA(h2(q01.y), w01, acc2[1]);
        acc2[2] = PKFMA(h2(q01.z), w01, acc2[2]);
        acc2[3] = PKFMA(h2(q01.w), w01, acc2[3]);
        acc2[0] = PKFMA(h2(q11.x), w11, acc2[0]);
        acc2[1] = PKFMA(h2(q11.y), w11, acc2[1]);
        acc2[2] = PKFMA(h2(q11.z), w11, acc2[2]);
        acc2[3] = PKFMA(h2(q11.w), w11, acc2[3]);
    }

    // ---- widen to f32, in-block reduction over 4 h-phases, exclusive store
    float acc[BB];
#pragma unroll
    for (int j = 0; j < 4; ++j) {
        acc[2 * j]     = (float)acc2[j].x;
        acc[2 * j + 1] = (float)acc2[j].y;
    }

    __shared__ float part[4][64][BB];        // 8 KB
#pragma unroll
    for (int b = 0; b < BB; b += 4)
        *(float4*)&part[g][lane][b] = make_float4(acc[b], acc[b + 1], acc[b + 2], acc[b + 3]);
    __syncthreads();

    const float sc = 1.0f / 256.0f;
#pragma unroll
    for (int k = 0; k < 2; ++k) {
        const int id = threadIdx.x + k * 256;  // 0..511 -> (b, wl)
        const int b  = id >> 6;
        const int wl = id & 63;
        const float v = part[0][wl][b] + part[1][wl][b] + part[2][wl][b] + part[3][wl][b];
        out[(size_t)b * NA * DD + (size_t)a * DD + wseg * 64 + wl] = v * sc;
    }
}

// ---- fallback (ws too small): direct fp32 gather with atomics -------------
__global__ __launch_bounds__(256) void radon_direct(const float* __restrict__ x,
                                                    float* __restrict__ out) {
    const int a  = blockIdx.x;
    const int hc = blockIdx.y;
    const int w  = threadIdx.x;
    const float ang = (float)a * 0.5f;
    const float t = ang * 0.017453292519943295f;
    const float s = sinf(t);
    const float c = cosf(t);
    const float uw = (float)w - 127.5f;
    const float ax = fmaf(c, uw, 127.5f);
    const float ay = fmaf(s, uw, 127.5f);

    float acc[BB];
#pragma unroll
    for (int b = 0; b < BB; ++b) acc[b] = 0.f;

    const int h0 = hc * 32;
    for (int i = 0; i < 32; ++i) {
        const float uh = (float)(h0 + i) - 127.5f;
        const float ix = fmaf(-s, uh, ax);
        const float iy = fmaf(c, uh, ay);
        const float x0f = floorf(ix), y0f = floorf(iy);
        const float wx1 = ix - x0f, wy1 = iy - y0f;
        const float wx0 = 1.f - wx1, wy0 = 1.f - wy1;
        const int x0 = (int)x0f, y0 = (int)y0f;
        const float vx0 = ((unsigned)x0 < 256u) ? wx0 : 0.f;
        const float vx1 = ((unsigned)(x0 + 1) < 256u) ? wx1 : 0.f;
        const float vy0 = ((unsigned)y0 < 256u) ? wy0 : 0.f;
        const float vy1 = ((unsigned)(y0 + 1) < 256u) ? wy1 : 0.f;
        const int x0c = min(max(x0, 0), 255);
        const int x1c = min(max(x0 + 1, 0), 255);
        const int y0c = min(max(y0, 0), 255);
        const int y1c = min(max(y0 + 1, 0), 255);
        const float w00 = vx0 * vy0, w10 = vx1 * vy0;
        const float w01 = vx0 * vy1, w11 = vx1 * vy1;
        const int l00 = y0c * DD + x0c, l10 = y0c * DD + x1c;
        const int l01 = y1c * DD + x0c, l11 = y1c * DD + x1c;
#pragma unroll
        for (int b = 0; b < BB; ++b) {
            const float* ib = x + (size_t)b * DD * DD;
            acc[b] = fmaf(ib[l00], w00, acc[b]);
            acc[b] = fmaf(ib[l10], w10, acc[b]);
            acc[b] = fmaf(ib[l01], w01, acc[b]);
            acc[b] = fmaf(ib[l11], w11, acc[b]);
        }
    }

    const float sc = 1.0f / 256.0f;
    float* o = out + (size_t)a * DD + w;
#pragma unroll
    for (int b = 0; b < BB; ++b)
        atomicAdd(o + (size_t)b * NA * DD, acc[b] * sc);
}

extern "C" void kernel_launch(void* const* d_in, const int* in_sizes, int n_in,
                              void* d_out, int out_size, void* d_ws, size_t ws_size,
                              hipStream_t stream) {
    const float* x = (const float*)d_in[0];
    float* out = (float*)d_out;

    const size_t need = 2ull * DD * DD * sizeof(uint4);  // 2 MiB
    if (ws_size >= need) {
        uint4* pN = (uint4*)d_ws;
        uint4* pT = pN + (size_t)DD * DD;
        pack_f16<<<64, 256, 0, stream>>>(x, pN, pT);
        radon_pk<<<dim3(NA, 4), 256, 0, stream>>>(pN, pT, out);
    } else {
        (void)hipMemsetAsync(d_out, 0, (size_t)out_size * sizeof(float), stream);
        radon_direct<<<dim3(NA, 8), 256, 0, stream>>>(x, out);
    }
}